// Round 17
// baseline (99.363 us; speedup 1.0000x reference)
//
#include <hip/hip_runtime.h>
#include <stdint.h>

#define BB 128
#define SS 4096
#define DD 64
#define HH 256

typedef short bf16x8 __attribute__((ext_vector_type(8)));
typedef float f32x16 __attribute__((ext_vector_type(16)));
typedef float f32x2 __attribute__((ext_vector_type(2)));

__device__ __forceinline__ uint32_t cvt_pk_bf16(float lo, float hi) {
  uint32_t r;
  asm("v_cvt_pk_bf16_f32 %0, %1, %2" : "=v"(r) : "v"(lo), "v"(hi));
  return r;
}

__device__ __forceinline__ float bflo(uint32_t w) {
  union { uint32_t u; float f; } c; c.u = w << 16; return c.f;
}
__device__ __forceinline__ float bfhi(uint32_t w) {
  union { uint32_t u; float f; } c; c.u = w & 0xffff0000u; return c.f;
}

// v_permlane32_swap_b32: new_a = [a.row0, b.row0], new_b = [a.row1, b.row1]
__device__ __forceinline__ void permswap(uint32_t& a, uint32_t& b) {
  asm("v_permlane32_swap_b32 %0, %1" : "+v"(a), "+v"(b));
}

// r14 silu (best measured): 2 trans + ~4 VALU per pair. r16's poly variant
// (1 trans + 8 VALU) REGRESSED — VALU issue is pricier than trans here.
__device__ __forceinline__ uint32_t silu2_pack(float a, float b) {
  f32x2 v = {a, b};
  f32x2 m = v * (-1.44269504f);          // v_pk_mul_f32
  float ea, eb;
  asm("v_exp_f32 %0, %1" : "=v"(ea) : "v"(m.x));
  asm("v_exp_f32 %0, %1" : "=v"(eb) : "v"(m.y));
  f32x2 d = {ea, eb};
  d = d + (f32x2){1.0f, 1.0f};           // v_pk_add_f32
  f32x2 r = {__builtin_amdgcn_rcpf(d.x), __builtin_amdgcn_rcpf(d.y)};
  f32x2 o = v * r;                       // v_pk_mul_f32
  return cvt_pk_bf16(o.x, o.y);
}

__device__ __forceinline__ void gload16(const void* g, void* l) {
  __builtin_amdgcn_global_load_lds(
      (const __attribute__((address_space(1))) void*)g,
      (__attribute__((address_space(3))) void*)l, 16, 0, 0);
}

// -------- pre-pass: weights -> FRAGMENT-MAJOR bf16 layout in workspace -----
// W1f: per b, 32 tiles (hc*4+kc) of 64 lanes x 16B:
//   lane holds W1[d = kc*16+(lane>>5)*8 + j][h = hc*32+(lane&31)], j=0..7
// W2f: per b, 32 tiles (hc*4+mt*2+c) of 64 lanes x 16B:
//   lane holds W2[h = hc*32+c*16+(lane>>5)*8 + j][d = mt*32+(lane&31)]
__global__ __launch_bounds__(256) void transpose_w(
    const float* __restrict__ W1, const float* __restrict__ W2,
    ushort* __restrict__ W1f, ushort* __restrict__ W2f) {
  int g = blockIdx.x * 256 + threadIdx.x;
  const int half = (BB * DD * HH) / 8;  // 262144
  float v[8];
  if (g < half) {
    size_t e = (size_t)g * 8;            // ushort index: b|tile|lane|j
    int b = (int)(e >> 14);
    int rem = (int)(e & 16383);
    int tile = rem >> 9;                 // hc*4 + kc
    int lane6 = (rem >> 3) & 63;
    int hc = tile >> 2, kc = tile & 3;
    int h = hc * 32 + (lane6 & 31);
    int d0 = kc * 16 + (lane6 >> 5) * 8;
    const float* src = W1 + ((size_t)b << 14) + h;  // + d*256
#pragma unroll
    for (int j = 0; j < 8; ++j) v[j] = src[(size_t)(d0 + j) << 8];
    uint4 o;
    o.x = cvt_pk_bf16(v[0], v[1]); o.y = cvt_pk_bf16(v[2], v[3]);
    o.z = cvt_pk_bf16(v[4], v[5]); o.w = cvt_pk_bf16(v[6], v[7]);
    *reinterpret_cast<uint4*>(W1f + e) = o;
  } else if (g < 2 * half) {
    size_t e = (size_t)(g - half) * 8;
    int b = (int)(e >> 14);
    int rem = (int)(e & 16383);
    int tile = rem >> 9;                 // hc*4 + mt*2 + c
    int lane6 = (rem >> 3) & 63;
    int hc = tile >> 2, mt = (tile >> 1) & 1, c = tile & 1;
    int d = mt * 32 + (lane6 & 31);
    int h0 = hc * 32 + c * 16 + (lane6 >> 5) * 8;
    const float* src = W2 + ((size_t)b << 14) + d;  // + h*64
#pragma unroll
    for (int j = 0; j < 8; ++j) v[j] = src[(size_t)(h0 + j) << 6];
    uint4 o;
    o.x = cvt_pk_bf16(v[0], v[1]); o.y = cvt_pk_bf16(v[2], v[3]);
    o.z = cvt_pk_bf16(v[4], v[5]); o.w = cvt_pk_bf16(v[6], v[7]);
    *reinterpret_cast<uint4*>(W2f + e) = o;
  }
}

// ---------------- main fused kernel (nt=2: 64-row waves) ----------------
// Block = 512 thr (8 waves), one b, 512 s-rows (wave = 64 rows, 2 subtiles).
// KEY CHANGE vs r14: each weight fragment is ds_read ONCE and feeds TWO
// MFMAs (nt=0,1) -> per-output weight-LDS traffic halves (LDS pipe was the
// largest pipe at ~29us/CU). Grid 1024 (8 blocks per b).
// LDS 64 KB: [0,32K) W1f frag-major | [32K,64K) x-stage (two 256-row
// halves, time-shared) then W2f frag-major.
__global__ __launch_bounds__(512, 3) void mlp_fused(
    const float* __restrict__ xg, const ushort* __restrict__ w1f,
    const ushort* __restrict__ w2f, float* __restrict__ outg) {
  __shared__ int4 lds4[65536 / 16];
  char* lds = (char*)lds4;

  const int tid = threadIdx.x;
  const int wave = tid >> 6;
  const int lane = tid & 63;
  const int l31 = lane & 31;
  const int g5 = lane >> 5;

  // 1024 blocks; XCD-aware swizzle (1024%8==0 -> bijective)
  int raw = blockIdx.x;
  int logical = (raw & 7) * 128 + (raw >> 3);
  const int b = logical >> 3;            // 8 blocks per b
  const int st = logical & 7;            // 512-row s-tile

  const char* w1b = (const char*)(w1f + ((size_t)b << 14));
  const char* w2b = (const char*)(w2f + ((size_t)b << 14));
  char* xlds = lds + 32768;

  // (1) issue W1f staging into region A (async, linear copy)
#pragma unroll
  for (int r = 0; r < 4; ++r) {
    uint32_t o = (uint32_t)(r * 8192 + tid * 16);
    gload16(w1b + o, lds + o);
  }

  const float* xblk = xg + (((size_t)b * SS + st * 512) << 6);

  bf16x8 bx[2][4];
  f32x16 acc[2][2];  // [nt][mt]

  // (2) stage x in two 256-row halves (32 KB each) through region B
#pragma unroll
  for (int half = 0; half < 2; ++half) {
    const float* xh = xblk + half * 16384;
#pragma unroll
    for (int ps = 0; ps < 4; ++ps) {
      int e = ps * 4096 + tid * 8;
      float4 fa = *reinterpret_cast<const float4*>(xh + e);
      float4 fb = *reinterpret_cast<const float4*>(xh + e + 4);
      uint4 pk;
      pk.x = cvt_pk_bf16(fa.x, fa.y);
      pk.y = cvt_pk_bf16(fa.z, fa.w);
      pk.z = cvt_pk_bf16(fb.x, fb.y);
      pk.w = cvt_pk_bf16(fb.z, fb.w);
      int row = e >> 6, d0 = e & 63;
      uint32_t byte = (uint32_t)(row * 128 + d0 * 2);
      byte ^= (uint32_t)(row & 15) << 4;   // 4-bit key: 2-way on reads
      *reinterpret_cast<uint4*>(xlds + byte) = pk;
    }
    __syncthreads();  // half staged (first pass also drains W1f)

    // waves owning this half read frags + residual
    if ((wave >> 2) == half) {
#pragma unroll
      for (int nt = 0; nt < 2; ++nt) {
        int r = ((wave & 3) * 64 + nt * 32 + l31) & 255;  // row within half
        uint32_t rs = (uint32_t)(r & 15) << 4;
#pragma unroll
        for (int kc = 0; kc < 4; ++kc) {
          uint32_t byte = (uint32_t)(r * 128 + kc * 32 + g5 * 16) ^ rs;
          bx[nt][kc] = *reinterpret_cast<const bf16x8*>(xlds + byte);
        }
#pragma unroll
        for (int mt = 0; mt < 2; ++mt)
#pragma unroll
          for (int q = 0; q < 4; ++q) {
            uint32_t byte =
                (uint32_t)(r * 128 + mt * 64 + q * 16 + g5 * 8) ^ rs;
            uint2 w = *reinterpret_cast<const uint2*>(xlds + byte);
            acc[nt][mt][4 * q + 0] = bflo(w.x);
            acc[nt][mt][4 * q + 1] = bfhi(w.x);
            acc[nt][mt][4 * q + 2] = bflo(w.y);
            acc[nt][mt][4 * q + 3] = bfhi(w.y);
          }
      }
    }
    __syncthreads();  // reads done; region B reusable
  }

  // (3) stage W2f into region B (linear async copy)
#pragma unroll
  for (int r = 0; r < 4; ++r) {
    uint32_t o = (uint32_t)(r * 8192 + tid * 16);
    gload16(w2b + o, xlds + o);
  }
  __syncthreads();  // W2f ready

  const char* lw1 = lds + lane * 16;
  const char* lw2 = xlds + lane * 16;

  const f32x16 vzero = {0.f, 0.f, 0.f, 0.f, 0.f, 0.f, 0.f, 0.f,
                        0.f, 0.f, 0.f, 0.f, 0.f, 0.f, 0.f, 0.f};

#pragma unroll
  for (int hc = 0; hc < 8; ++hc) {
    // ---- GEMM1: each a1 frag read ONCE, feeds both nt subtiles ----
    f32x16 ah0 = vzero, ah1 = vzero;
#pragma unroll
    for (int kc = 0; kc < 4; ++kc) {
      bf16x8 a1 = *reinterpret_cast<const bf16x8*>(lw1 + (hc * 4 + kc) * 1024);
      ah0 = __builtin_amdgcn_mfma_f32_32x32x16_bf16(a1, bx[0][kc], ah0, 0, 0, 0);
      ah1 = __builtin_amdgcn_mfma_f32_32x32x16_bf16(a1, bx[1][kc], ah1, 0, 0, 0);
    }

    // ---- silu + pack + permlane32_swap for both subtiles ----
    bf16x8 bh0[2], bh1[2];
#pragma unroll
    for (int c = 0; c < 2; ++c) {
      uint32_t A0 = silu2_pack(ah0[8 * c + 0], ah0[8 * c + 1]);
      uint32_t A1 = silu2_pack(ah0[8 * c + 2], ah0[8 * c + 3]);
      uint32_t B0 = silu2_pack(ah0[8 * c + 4], ah0[8 * c + 5]);
      uint32_t B1 = silu2_pack(ah0[8 * c + 6], ah0[8 * c + 7]);
      permswap(A0, B0);
      permswap(A1, B1);
      union { uint32_t u[4]; bf16x8 v; } f;
      f.u[0] = A0; f.u[1] = A1; f.u[2] = B0; f.u[3] = B1;
      bh0[c] = f.v;
    }
#pragma unroll
    for (int c = 0; c < 2; ++c) {
      uint32_t A0 = silu2_pack(ah1[8 * c + 0], ah1[8 * c + 1]);
      uint32_t A1 = silu2_pack(ah1[8 * c + 2], ah1[8 * c + 3]);
      uint32_t B0 = silu2_pack(ah1[8 * c + 4], ah1[8 * c + 5]);
      uint32_t B1 = silu2_pack(ah1[8 * c + 6], ah1[8 * c + 7]);
      permswap(A0, B0);
      permswap(A1, B1);
      union { uint32_t u[4]; bf16x8 v; } f;
      f.u[0] = A0; f.u[1] = A1; f.u[2] = B0; f.u[3] = B1;
      bh1[c] = f.v;
    }

    // ---- GEMM2: each a2 frag read ONCE, feeds both nt subtiles ----
#pragma unroll
    for (int c = 0; c < 2; ++c)
#pragma unroll
      for (int mt = 0; mt < 2; ++mt) {
        bf16x8 a2 = *reinterpret_cast<const bf16x8*>(
            lw2 + (hc * 4 + mt * 2 + c) * 1024);
        acc[0][mt] =
            __builtin_amdgcn_mfma_f32_32x32x16_bf16(a2, bh0[c], acc[0][mt], 0, 0, 0);
        acc[1][mt] =
            __builtin_amdgcn_mfma_f32_32x32x16_bf16(a2, bh1[c], acc[1][mt], 0, 0, 0);
      }
  }

  __syncthreads();  // weight LDS dead; reuse for out bounce

  // (4) epilogue: two nt passes; wave-private 8 KB slice; coalesced stores
  char* slice = lds + wave * 8192;  // 32 rows x 256 B
#pragma unroll
  for (int nt = 0; nt < 2; ++nt) {
    uint32_t sw = (uint32_t)(l31 & 15) << 4;
#pragma unroll
    for (int mt = 0; mt < 2; ++mt)
#pragma unroll
      for (int q = 0; q < 4; ++q) {
        uint32_t byte =
            ((uint32_t)(l31 * 256 + mt * 128 + q * 32 + g5 * 16)) ^ sw;
        float4 v;
        v.x = acc[nt][mt][4 * q + 0];
        v.y = acc[nt][mt][4 * q + 1];
        v.z = acc[nt][mt][4 * q + 2];
        v.w = acc[nt][mt][4 * q + 3];
        *reinterpret_cast<float4*>(slice + byte) = v;
      }
    __builtin_amdgcn_sched_barrier(0);
    float* orow =
        outg + (((size_t)b * SS + st * 512 + wave * 64 + nt * 32) << 6);
#pragma unroll
    for (int it = 0; it < 8; ++it) {
      uint32_t o = (uint32_t)(it * 1024 + lane * 16);
      uint32_t row = o >> 8;
      uint32_t byte = o ^ ((row & 15) << 4);
      float4 v = *reinterpret_cast<const float4*>(slice + byte);
      *reinterpret_cast<float4*>(orow + ((size_t)row << 6) + ((o & 255) >> 2)) =
          v;
    }
    __builtin_amdgcn_sched_barrier(0);
  }
}

extern "C" void kernel_launch(void* const* d_in, const int* in_sizes, int n_in,
                              void* d_out, int out_size, void* d_ws, size_t ws_size,
                              hipStream_t stream) {
  const float* x  = (const float*)d_in[0];
  const float* W1 = (const float*)d_in[1];
  const float* W2 = (const float*)d_in[2];
  float* out = (float*)d_out;

  ushort* W1f = (ushort*)d_ws;                       // bf16 frag-major, 4 MB
  ushort* W2f = W1f + (size_t)BB * DD * HH;          // bf16 frag-major, 4 MB

  transpose_w<<<2048, 256, 0, stream>>>(W1, W2, W1f, W2f);
  mlp_fused<<<1024, 512, 0, stream>>>(x, W1f, W2f, out);
}

// Round 18
// 83.274 us; speedup vs baseline: 1.1932x; 1.1932x over previous
//
#include <hip/hip_runtime.h>
#include <stdint.h>

#define BB 128
#define SS 4096
#define DD 64
#define HH 256

typedef short bf16x8 __attribute__((ext_vector_type(8)));
typedef float f32x16 __attribute__((ext_vector_type(16)));
typedef float f32x2 __attribute__((ext_vector_type(2)));

__device__ __forceinline__ uint32_t cvt_pk_bf16(float lo, float hi) {
  uint32_t r;
  asm("v_cvt_pk_bf16_f32 %0, %1, %2" : "=v"(r) : "v"(lo), "v"(hi));
  return r;
}

__device__ __forceinline__ float bflo(uint32_t w) {
  union { uint32_t u; float f; } c; c.u = w << 16; return c.f;
}
__device__ __forceinline__ float bfhi(uint32_t w) {
  union { uint32_t u; float f; } c; c.u = w & 0xffff0000u; return c.f;
}

// v_permlane32_swap_b32: new_a = [a.row0, b.row0], new_b = [a.row1, b.row1]
__device__ __forceinline__ void permswap(uint32_t& a, uint32_t& b) {
  asm("v_permlane32_swap_b32 %0, %1" : "+v"(a), "+v"(b));
}

// r14 silu (best measured): 2 exp + 2 rcp + 3 pk-VALU per pair.
__device__ __forceinline__ uint32_t silu2_pack(float a, float b) {
  f32x2 v = {a, b};
  f32x2 m = v * (-1.44269504f);
  float ea, eb;
  asm("v_exp_f32 %0, %1" : "=v"(ea) : "v"(m.x));
  asm("v_exp_f32 %0, %1" : "=v"(eb) : "v"(m.y));
  f32x2 d = {ea, eb};
  d = d + (f32x2){1.0f, 1.0f};
  f32x2 r = {__builtin_amdgcn_rcpf(d.x), __builtin_amdgcn_rcpf(d.y)};
  f32x2 o = v * r;
  return cvt_pk_bf16(o.x, o.y);
}

__device__ __forceinline__ void gload16(const void* g, void* l) {
  __builtin_amdgcn_global_load_lds(
      (const __attribute__((address_space(1))) void*)g,
      (__attribute__((address_space(3))) void*)l, 16, 0, 0);
}

// -------- pre-pass: weights -> FRAGMENT-MAJOR bf16 layout in workspace -----
// W1f: per b, 32 tiles (hc*4+kc) of 64 lanes x 16B:
//   lane holds W1[d = kc*16+(lane>>5)*8 + j][h = hc*32+(lane&31)], j=0..7
// W2f: per b, 32 tiles (hc*4+mt*2+c) of 64 lanes x 16B:
//   lane holds W2[h = hc*32+c*16+(lane>>5)*8 + j][d = mt*32+(lane&31)]
__global__ __launch_bounds__(256) void transpose_w(
    const float* __restrict__ W1, const float* __restrict__ W2,
    ushort* __restrict__ W1f, ushort* __restrict__ W2f) {
  int g = blockIdx.x * 256 + threadIdx.x;
  const int half = (BB * DD * HH) / 8;  // 262144
  float v[8];
  if (g < half) {
    size_t e = (size_t)g * 8;            // ushort index: b|tile|lane|j
    int b = (int)(e >> 14);
    int rem = (int)(e & 16383);
    int tile = rem >> 9;                 // hc*4 + kc
    int lane6 = (rem >> 3) & 63;
    int hc = tile >> 2, kc = tile & 3;
    int h = hc * 32 + (lane6 & 31);
    int d0 = kc * 16 + (lane6 >> 5) * 8;
    const float* src = W1 + ((size_t)b << 14) + h;  // + d*256
#pragma unroll
    for (int j = 0; j < 8; ++j) v[j] = src[(size_t)(d0 + j) << 8];
    uint4 o;
    o.x = cvt_pk_bf16(v[0], v[1]); o.y = cvt_pk_bf16(v[2], v[3]);
    o.z = cvt_pk_bf16(v[4], v[5]); o.w = cvt_pk_bf16(v[6], v[7]);
    *reinterpret_cast<uint4*>(W1f + e) = o;
  } else if (g < 2 * half) {
    size_t e = (size_t)(g - half) * 8;
    int b = (int)(e >> 14);
    int rem = (int)(e & 16383);
    int tile = rem >> 9;                 // hc*4 + mt*2 + c
    int lane6 = (rem >> 3) & 63;
    int hc = tile >> 2, mt = (tile >> 1) & 1, c = tile & 1;
    int d = mt * 32 + (lane6 & 31);
    int h0 = hc * 32 + c * 16 + (lane6 >> 5) * 8;
    const float* src = W2 + ((size_t)b << 14) + d;  // + h*64
#pragma unroll
    for (int j = 0; j < 8; ++j) v[j] = src[(size_t)(h0 + j) << 6];
    uint4 o;
    o.x = cvt_pk_bf16(v[0], v[1]); o.y = cvt_pk_bf16(v[2], v[3]);
    o.z = cvt_pk_bf16(v[4], v[5]); o.w = cvt_pk_bf16(v[6], v[7]);
    *reinterpret_cast<uint4*>(W2f + e) = o;
  }
}

// ---------------- main fused kernel (r14 structure, 48 KB LDS) ----------
// Block = 512 thr (8 waves), one b, 256 s-rows (wave = 32 rows).
// LDS 48 KB -> 3 blocks/CU (24 waves, vs r14's 64 KB / 2 blocks / 16 waves):
//   [0,32K)   W1f frag-major (whole kernel); epilogue bounce after main loop
//   [32K,48K) time-shared 16KB: x-stage (two 128-row halves) -> W2f half 0
//             (hc 0-3) -> W2f half 1 (hc 4-7, one mid-loop re-stage)
// Per-wave cost identical to r14 (the r10/r17 failure modes avoided).
__global__ __launch_bounds__(512) void mlp_fused(
    const float* __restrict__ xg, const ushort* __restrict__ w1f,
    const ushort* __restrict__ w2f, float* __restrict__ outg) {
  __shared__ int4 lds4[49152 / 16];
  char* lds = (char*)lds4;

  const int tid = threadIdx.x;
  const int wave = tid >> 6;
  const int lane = tid & 63;
  const int l31 = lane & 31;
  const int g5 = lane >> 5;

  // 2048 blocks; XCD-aware swizzle: XCD k owns b in [16k, 16k+16)
  int raw = blockIdx.x;
  int logical = (raw & 7) * 256 + (raw >> 3);
  const int b = logical >> 4;            // 16 blocks per b
  const int st = logical & 15;
  const int s_base = st * 256 + wave * 32;

  const char* w1b = (const char*)(w1f + ((size_t)b << 14));
  const char* w2b = (const char*)(w2f + ((size_t)b << 14));
  char* xlds = lds + 32768;  // 16 KB region B

  // (1) issue W1f staging into region A (async, linear copy)
#pragma unroll
  for (int r = 0; r < 4; ++r) {
    uint32_t o = (uint32_t)(r * 8192 + tid * 16);
    gload16(w1b + o, lds + o);
  }

  const float* xblk = xg + (((size_t)b * SS + st * 256) << 6);

  bf16x8 bx[4];
  f32x16 acc[2];

  // (2) stage x in two 128-row halves (16 KB each) through region B
#pragma unroll
  for (int hf = 0; hf < 2; ++hf) {
    const float* xh = xblk + hf * 8192;  // 128 rows x 64 f32
#pragma unroll
    for (int ps = 0; ps < 2; ++ps) {
      int e = ps * 4096 + tid * 8;
      float4 fa = *reinterpret_cast<const float4*>(xh + e);
      float4 fb = *reinterpret_cast<const float4*>(xh + e + 4);
      uint4 pk;
      pk.x = cvt_pk_bf16(fa.x, fa.y);
      pk.y = cvt_pk_bf16(fa.z, fa.w);
      pk.z = cvt_pk_bf16(fb.x, fb.y);
      pk.w = cvt_pk_bf16(fb.z, fb.w);
      int row = e >> 6, d0 = e & 63;
      uint32_t byte = (uint32_t)(row * 128 + d0 * 2);
      byte ^= (uint32_t)(row & 7) << 4;
      *reinterpret_cast<uint4*>(xlds + byte) = pk;
    }
    __syncthreads();  // half staged (first pass also drains W1f gloads)

    // waves owning this half read frags + residual
    if ((wave >> 2) == hf) {
      int r = (wave & 3) * 32 + l31;  // row within half, 0..127
      uint32_t rs = (uint32_t)(r & 7) << 4;
#pragma unroll
      for (int kc = 0; kc < 4; ++kc) {
        uint32_t byte = (uint32_t)(r * 128 + kc * 32 + g5 * 16) ^ rs;
        bx[kc] = *reinterpret_cast<const bf16x8*>(xlds + byte);
      }
#pragma unroll
      for (int mt = 0; mt < 2; ++mt)
#pragma unroll
        for (int q = 0; q < 4; ++q) {
          uint32_t byte = (uint32_t)(r * 128 + mt * 64 + q * 16 + g5 * 8) ^ rs;
          uint2 w = *reinterpret_cast<const uint2*>(xlds + byte);
          acc[mt][4 * q + 0] = bflo(w.x);
          acc[mt][4 * q + 1] = bfhi(w.x);
          acc[mt][4 * q + 2] = bflo(w.y);
          acc[mt][4 * q + 3] = bfhi(w.y);
        }
    }
    __syncthreads();  // reads done; region B reusable
  }

  // (3) stage W2f half 0 (tiles hc 0-3, 16 KB) into region B
#pragma unroll
  for (int r = 0; r < 2; ++r) {
    uint32_t o = (uint32_t)(r * 8192 + tid * 16);
    gload16(w2b + o, xlds + o);
  }
  __syncthreads();

  const char* lw1 = lds + lane * 16;
  const char* lw2 = xlds + lane * 16;

  const f32x16 vzero = {0.f, 0.f, 0.f, 0.f, 0.f, 0.f, 0.f, 0.f,
                        0.f, 0.f, 0.f, 0.f, 0.f, 0.f, 0.f, 0.f};

#pragma unroll
  for (int ph = 0; ph < 2; ++ph) {
#pragma unroll
    for (int hq = 0; hq < 4; ++hq) {
      const int hc = ph * 4 + hq;
      // ---- GEMM1 (swapped, 32h x 32s) ----
      f32x16 ah = vzero;
#pragma unroll
      for (int kc = 0; kc < 4; ++kc) {
        bf16x8 a1 =
            *reinterpret_cast<const bf16x8*>(lw1 + (hc * 4 + kc) * 1024);
        ah = __builtin_amdgcn_mfma_f32_32x32x16_bf16(a1, bx[kc], ah, 0, 0, 0);
      }

      // ---- silu + pack + permlane32_swap -> GEMM2 B-frags ----
      bf16x8 bh[2];
#pragma unroll
      for (int c = 0; c < 2; ++c) {
        uint32_t A0 = silu2_pack(ah[8 * c + 0], ah[8 * c + 1]);
        uint32_t A1 = silu2_pack(ah[8 * c + 2], ah[8 * c + 3]);
        uint32_t B0 = silu2_pack(ah[8 * c + 4], ah[8 * c + 5]);
        uint32_t B1 = silu2_pack(ah[8 * c + 6], ah[8 * c + 7]);
        permswap(A0, B0);
        permswap(A1, B1);
        union { uint32_t u[4]; bf16x8 v; } f;
        f.u[0] = A0; f.u[1] = A1; f.u[2] = B0; f.u[3] = B1;
        bh[c] = f.v;
      }

      // ---- GEMM2 (swapped), a2 from the resident W2f half ----
#pragma unroll
      for (int c = 0; c < 2; ++c)
#pragma unroll
        for (int mt = 0; mt < 2; ++mt) {
          bf16x8 a2 = *reinterpret_cast<const bf16x8*>(
              lw2 + (hq * 4 + mt * 2 + c) * 1024);
          acc[mt] = __builtin_amdgcn_mfma_f32_32x32x16_bf16(a2, bh[c], acc[mt],
                                                            0, 0, 0);
        }
    }

    if (ph == 0) {
      __syncthreads();  // all waves done with W2f half 0
#pragma unroll
      for (int r = 0; r < 2; ++r) {
        uint32_t o = (uint32_t)(r * 8192 + tid * 16);
        gload16(w2b + 16384 + o, xlds + o);  // tiles hc 4-7
      }
      __syncthreads();  // W2f half 1 ready
    }
  }

  __syncthreads();  // W1f region dead; reuse for out bounce

  // (4) epilogue: two mt passes; per-wave 4 KB slice; coalesced-ish stores
  char* slice = lds + wave * 4096;  // 32 rows x 128 B
  float* orow = outg + (((size_t)b * SS + s_base) << 6);
#pragma unroll
  for (int mt = 0; mt < 2; ++mt) {
    uint32_t sw = (uint32_t)(l31 & 7) << 4;
#pragma unroll
    for (int q = 0; q < 4; ++q) {
      uint32_t byte = ((uint32_t)(l31 * 128 + q * 32 + g5 * 16)) ^ sw;
      float4 v;
      v.x = acc[mt][4 * q + 0];
      v.y = acc[mt][4 * q + 1];
      v.z = acc[mt][4 * q + 2];
      v.w = acc[mt][4 * q + 3];
      *reinterpret_cast<float4*>(slice + byte) = v;
    }
    __builtin_amdgcn_sched_barrier(0);
#pragma unroll
    for (int it = 0; it < 4; ++it) {
      uint32_t o = (uint32_t)(it * 1024 + lane * 16);
      uint32_t row = o >> 7;
      uint32_t byte = o ^ ((row & 7) << 4);
      float4 v = *reinterpret_cast<const float4*>(slice + byte);
      *reinterpret_cast<float4*>(orow + ((size_t)row << 6) + mt * 32 +
                                 ((o & 127) >> 2)) = v;
    }
    __builtin_amdgcn_sched_barrier(0);
  }
}

extern "C" void kernel_launch(void* const* d_in, const int* in_sizes, int n_in,
                              void* d_out, int out_size, void* d_ws, size_t ws_size,
                              hipStream_t stream) {
  const float* x  = (const float*)d_in[0];
  const float* W1 = (const float*)d_in[1];
  const float* W2 = (const float*)d_in[2];
  float* out = (float*)d_out;

  ushort* W1f = (ushort*)d_ws;                       // bf16 frag-major, 4 MB
  ushort* W2f = W1f + (size_t)BB * DD * HH;          // bf16 frag-major, 4 MB

  transpose_w<<<2048, 256, 0, stream>>>(W1, W2, W1f, W2f);
  mlp_fused<<<2048, 512, 0, stream>>>(x, W1f, W2f, out);
}

// Round 19
// 78.773 us; speedup vs baseline: 1.2614x; 1.0571x over previous
//
#include <hip/hip_runtime.h>
#include <stdint.h>

#define BB 128
#define SS 4096
#define DD 64
#define HH 256

typedef short bf16x8 __attribute__((ext_vector_type(8)));
typedef float f32x16 __attribute__((ext_vector_type(16)));
typedef float f32x2 __attribute__((ext_vector_type(2)));

__device__ __forceinline__ uint32_t cvt_pk_bf16(float lo, float hi) {
  uint32_t r;
  asm("v_cvt_pk_bf16_f32 %0, %1, %2" : "=v"(r) : "v"(lo), "v"(hi));
  return r;
}

__device__ __forceinline__ float bflo(uint32_t w) {
  union { uint32_t u; float f; } c; c.u = w << 16; return c.f;
}
__device__ __forceinline__ float bfhi(uint32_t w) {
  union { uint32_t u; float f; } c; c.u = w & 0xffff0000u; return c.f;
}

// v_permlane32_swap_b32: new_a = [a.row0, b.row0], new_b = [a.row1, b.row1]
__device__ __forceinline__ void permswap(uint32_t& a, uint32_t& b) {
  asm("v_permlane32_swap_b32 %0, %1" : "+v"(a), "+v"(b));
}

// packed-f32 silu on a pair, returns packed bf16 word.
__device__ __forceinline__ uint32_t silu2_pack(float a, float b) {
  f32x2 v = {a, b};
  f32x2 m = v * (-1.44269504f);          // v_pk_mul_f32
  float ea, eb;
  asm("v_exp_f32 %0, %1" : "=v"(ea) : "v"(m.x));
  asm("v_exp_f32 %0, %1" : "=v"(eb) : "v"(m.y));
  f32x2 d = {ea, eb};
  d = d + (f32x2){1.0f, 1.0f};           // v_pk_add_f32
  f32x2 r = {__builtin_amdgcn_rcpf(d.x), __builtin_amdgcn_rcpf(d.y)};
  f32x2 o = v * r;                       // v_pk_mul_f32
  return cvt_pk_bf16(o.x, o.y);
}

__device__ __forceinline__ void gload16(const void* g, void* l) {
  __builtin_amdgcn_global_load_lds(
      (const __attribute__((address_space(1))) void*)g,
      (__attribute__((address_space(3))) void*)l, 16, 0, 0);
}

// -------- pre-pass: weights -> FRAGMENT-MAJOR bf16 layout in workspace -----
// W1f: per b, 32 tiles (hc*4+kc) of 64 lanes x 16B:
//   lane holds W1[d = kc*16+(lane>>5)*8 + j][h = hc*32+(lane&31)], j=0..7
// W2f: per b, 32 tiles (hc*4+mt*2+c) of 64 lanes x 16B:
//   lane holds W2[h = hc*32+c*16+(lane>>5)*8 + j][d = mt*32+(lane&31)]
__global__ __launch_bounds__(256) void transpose_w(
    const float* __restrict__ W1, const float* __restrict__ W2,
    ushort* __restrict__ W1f, ushort* __restrict__ W2f) {
  int g = blockIdx.x * 256 + threadIdx.x;
  const int half = (BB * DD * HH) / 8;  // 262144
  float v[8];
  if (g < half) {
    size_t e = (size_t)g * 8;            // ushort index: b|tile|lane|j
    int b = (int)(e >> 14);
    int rem = (int)(e & 16383);
    int tile = rem >> 9;                 // hc*4 + kc
    int lane6 = (rem >> 3) & 63;
    int hc = tile >> 2, kc = tile & 3;
    int h = hc * 32 + (lane6 & 31);
    int d0 = kc * 16 + (lane6 >> 5) * 8;
    const float* src = W1 + ((size_t)b << 14) + h;  // + d*256
#pragma unroll
    for (int j = 0; j < 8; ++j) v[j] = src[(size_t)(d0 + j) << 8];
    uint4 o;
    o.x = cvt_pk_bf16(v[0], v[1]); o.y = cvt_pk_bf16(v[2], v[3]);
    o.z = cvt_pk_bf16(v[4], v[5]); o.w = cvt_pk_bf16(v[6], v[7]);
    *reinterpret_cast<uint4*>(W1f + e) = o;
  } else if (g < 2 * half) {
    size_t e = (size_t)(g - half) * 8;
    int b = (int)(e >> 14);
    int rem = (int)(e & 16383);
    int tile = rem >> 9;                 // hc*4 + mt*2 + c
    int lane6 = (rem >> 3) & 63;
    int hc = tile >> 2, mt = (tile >> 1) & 1, c = tile & 1;
    int d = mt * 32 + (lane6 & 31);
    int h0 = hc * 32 + c * 16 + (lane6 >> 5) * 8;
    const float* src = W2 + ((size_t)b << 14) + d;  // + h*64
#pragma unroll
    for (int j = 0; j < 8; ++j) v[j] = src[(size_t)(h0 + j) << 6];
    uint4 o;
    o.x = cvt_pk_bf16(v[0], v[1]); o.y = cvt_pk_bf16(v[2], v[3]);
    o.z = cvt_pk_bf16(v[4], v[5]); o.w = cvt_pk_bf16(v[6], v[7]);
    *reinterpret_cast<uint4*>(W2f + e) = o;
  }
}

// ---------------- main fused kernel (round-14 champion, 79.0 us) ----------
// Block = 512 thr (8 waves), one b, 256 s-rows (wave = 32 rows).
// All global traffic coalesced:
//   x: coalesced 32B/thread f32 reads -> bf16 LDS tile (time-shares the
//      W2f region before W2f is staged), frags + residual read from LDS.
//   out: f32 bounce through the (dead) weight LDS -> 1KB-contiguous stores.
// LDS 64 KB: [0,32K) W1f frag-major | [32K,64K) x-stage then W2f frag-major.
// Main loop: ds_read_b128 at lane*16+literal (0 addr math, 0 conflicts);
// in-register GEMM1->GEMM2 conversion (cvt_pk + permlane32_swap);
// packed-f32 silu (2 trans + 3 pk-VALU per pair — r16's poly variant lost).
__global__ __launch_bounds__(512, 4) void mlp_fused(
    const float* __restrict__ xg, const ushort* __restrict__ w1f,
    const ushort* __restrict__ w2f, float* __restrict__ outg) {
  __shared__ int4 lds4[65536 / 16];
  char* lds = (char*)lds4;

  const int tid = threadIdx.x;
  const int wave = tid >> 6;
  const int lane = tid & 63;
  const int l31 = lane & 31;
  const int g5 = lane >> 5;

  // 2048 blocks; XCD-aware swizzle: XCD k owns b in [16k, 16k+16)
  int raw = blockIdx.x;
  int logical = (raw & 7) * 256 + (raw >> 3);
  const int b = logical >> 4;            // 16 blocks per b
  const int st = logical & 15;
  const int s_base = st * 256 + wave * 32;

  const char* w1b = (const char*)(w1f + ((size_t)b << 14));
  const char* w2b = (const char*)(w2f + ((size_t)b << 14));
  char* xlds = lds + 32768;

  // (1) issue W1f staging into region A (async, linear copy)
#pragma unroll
  for (int r = 0; r < 4; ++r) {
    uint32_t o = (uint32_t)(r * 8192 + tid * 16);
    gload16(w1b + o, lds + o);
  }

  // (2) stage x tile (256 rows x 64 d) f32->bf16 into region B, COALESCED
  const float* xblk = xg + (((size_t)b * SS + st * 256) << 6);
#pragma unroll
  for (int ps = 0; ps < 4; ++ps) {
    int e = ps * 4096 + tid * 8;
    float4 fa = *reinterpret_cast<const float4*>(xblk + e);
    float4 fb = *reinterpret_cast<const float4*>(xblk + e + 4);
    uint4 pk;
    pk.x = cvt_pk_bf16(fa.x, fa.y);
    pk.y = cvt_pk_bf16(fa.z, fa.w);
    pk.z = cvt_pk_bf16(fb.x, fb.y);
    pk.w = cvt_pk_bf16(fb.z, fb.w);
    int row = e >> 6, d0 = e & 63;
    uint32_t byte = (uint32_t)(row * 128 + d0 * 2);
    byte ^= (uint32_t)(row & 7) << 4;
    *reinterpret_cast<uint4*>(xlds + byte) = pk;
  }

  __syncthreads();  // x tile in LDS (W1f also drained)

  // (3) frags + residual from LDS (wave-local rows R = 32*wave + l31)
  const int R = wave * 32 + l31;
  const uint32_t rs = (uint32_t)(R & 7) << 4;

  bf16x8 bx[4];
#pragma unroll
  for (int kc = 0; kc < 4; ++kc) {
    uint32_t byte = (uint32_t)(R * 128 + kc * 32 + g5 * 16) ^ rs;
    bx[kc] = *reinterpret_cast<const bf16x8*>(xlds + byte);
  }

  f32x16 acc[2];  // residual init (bf16-rounded; error budget OK)
#pragma unroll
  for (int mt = 0; mt < 2; ++mt)
#pragma unroll
    for (int q = 0; q < 4; ++q) {
      uint32_t byte = (uint32_t)(R * 128 + mt * 64 + q * 16 + g5 * 8) ^ rs;
      uint2 w = *reinterpret_cast<const uint2*>(xlds + byte);
      acc[mt][4 * q + 0] = bflo(w.x);
      acc[mt][4 * q + 1] = bfhi(w.x);
      acc[mt][4 * q + 2] = bflo(w.y);
      acc[mt][4 * q + 3] = bfhi(w.y);
    }

  __syncthreads();  // all reads of x-stage done; region B reusable

  // (4) stage W2f into region B (linear async copy)
#pragma unroll
  for (int r = 0; r < 4; ++r) {
    uint32_t o = (uint32_t)(r * 8192 + tid * 16);
    gload16(w2b + o, xlds + o);
  }

  __syncthreads();  // W2f ready

  const char* lw1 = lds + lane * 16;
  const char* lw2 = xlds + lane * 16;

  const f32x16 vzero = {0.f, 0.f, 0.f, 0.f, 0.f, 0.f, 0.f, 0.f,
                        0.f, 0.f, 0.f, 0.f, 0.f, 0.f, 0.f, 0.f};

#pragma unroll
  for (int hc = 0; hc < 8; ++hc) {
    // ---- GEMM1 (swapped, 32h x 32s) ----
    f32x16 ah = vzero;
#pragma unroll
    for (int kc = 0; kc < 4; ++kc) {
      bf16x8 a1 = *reinterpret_cast<const bf16x8*>(lw1 + (hc * 4 + kc) * 1024);
      ah = __builtin_amdgcn_mfma_f32_32x32x16_bf16(a1, bx[kc], ah, 0, 0, 0);
    }

    // ---- silu (packed) + pack + permlane32_swap -> GEMM2 B-frags ----
    bf16x8 bh[2];
#pragma unroll
    for (int c = 0; c < 2; ++c) {
      uint32_t A0 = silu2_pack(ah[8 * c + 0], ah[8 * c + 1]);
      uint32_t A1 = silu2_pack(ah[8 * c + 2], ah[8 * c + 3]);
      uint32_t B0 = silu2_pack(ah[8 * c + 4], ah[8 * c + 5]);
      uint32_t B1 = silu2_pack(ah[8 * c + 6], ah[8 * c + 7]);
      permswap(A0, B0);
      permswap(A1, B1);
      union { uint32_t u[4]; bf16x8 v; } f;
      f.u[0] = A0; f.u[1] = A1; f.u[2] = B0; f.u[3] = B1;
      bh[c] = f.v;
    }

    // ---- GEMM2 (swapped) ----
#pragma unroll
    for (int c = 0; c < 2; ++c)
#pragma unroll
      for (int mt = 0; mt < 2; ++mt) {
        bf16x8 a2 = *reinterpret_cast<const bf16x8*>(
            lw2 + (hc * 4 + mt * 2 + c) * 1024);
        acc[mt] =
            __builtin_amdgcn_mfma_f32_32x32x16_bf16(a2, bh[c], acc[mt], 0, 0, 0);
      }
  }

  __syncthreads();  // weight LDS dead; reuse all 64 KB for out bounce

  // (5) epilogue: f32 out tile -> per-wave 8 KB LDS slice -> coalesced store
  char* slice = lds + wave * 8192;  // 32 rows x 256 B
  {
    uint32_t sw = (uint32_t)(l31 & 7) << 4;
#pragma unroll
    for (int mt = 0; mt < 2; ++mt)
#pragma unroll
      for (int q = 0; q < 4; ++q) {
        uint32_t byte =
            ((uint32_t)(l31 * 256 + mt * 128 + q * 32 + g5 * 16)) ^ sw;
        float4 v;
        v.x = acc[mt][4 * q + 0];
        v.y = acc[mt][4 * q + 1];
        v.z = acc[mt][4 * q + 2];
        v.w = acc[mt][4 * q + 3];
        *reinterpret_cast<float4*>(slice + byte) = v;
      }
  }
  __builtin_amdgcn_sched_barrier(0);
  {
    float* orow = outg + (((size_t)b * SS + s_base) << 6);
#pragma unroll
    for (int it = 0; it < 8; ++it) {
      uint32_t o = (uint32_t)(it * 1024 + lane * 16);
      uint32_t row = o >> 8;
      uint32_t byte = o ^ ((row & 7) << 4);
      float4 v = *reinterpret_cast<const float4*>(slice + byte);
      *reinterpret_cast<float4*>(orow + ((size_t)row << 6) + ((o & 255) >> 2)) =
          v;
    }
  }
}

extern "C" void kernel_launch(void* const* d_in, const int* in_sizes, int n_in,
                              void* d_out, int out_size, void* d_ws, size_t ws_size,
                              hipStream_t stream) {
  const float* x  = (const float*)d_in[0];
  const float* W1 = (const float*)d_in[1];
  const float* W2 = (const float*)d_in[2];
  float* out = (float*)d_out;

  ushort* W1f = (ushort*)d_ws;                       // bf16 frag-major, 4 MB
  ushort* W2f = W1f + (size_t)BB * DD * HH;          // bf16 frag-major, 4 MB

  transpose_w<<<2048, 256, 0, stream>>>(W1, W2, W1f, W2f);
  mlp_fused<<<2048, 512, 0, stream>>>(x, W1f, W2f, out);
}